// Round 11
// baseline (373.150 us; speedup 1.0000x reference)
//
#include <hip/hip_runtime.h>

#define NV 16384
#define JC 512            // j-chunk: 2 KB contiguous burst per row-visit
#define RPW 8             // rows per wave
#define NCH (NV / JC)     // 32 chunks

#define FENCE asm volatile("" ::: "memory")
#define WAITV(n) asm volatile("s_waitcnt vmcnt(" #n ")" ::: "memory")

// 1 wave per block, no LDS, no barriers; 2048 fully independent waves.
__global__ __launch_bounds__(64, 2) void lap_loss_kernel(
    const float* __restrict__ x, const float* __restrict__ L,
    float* __restrict__ out) {
  const int lane = threadIdx.x;
  const size_t i0 = (size_t)blockIdx.x * RPW;

  const float* Lb = L + i0 * NV + lane * 4;

  float acc[RPW][12];
#pragma unroll
  for (int r = 0; r < RPW; ++r)
#pragma unroll
    for (int k = 0; k < 12; ++k) acc[r][k] = 0.f;

  float4 xr[2][4][3];  // x chunk: [quad][batch][word], static indices only
  float4 lr[4][2];     // L row slots: [slot][quad], static indices only

// Row-chunk index nn (0..255): row nn&7, chunk nn>>3, slot literal.
#define ISSUE_L(nn, slot) do {                                              \
    const float* _lp =                                                      \
        Lb + (size_t)((nn) & 7) * NV + (size_t)((nn) >> 3) * JC;            \
    lr[slot][0] = *(const float4*)_lp;                                      \
    lr[slot][1] = *(const float4*)(_lp + 256);                              \
  } while (0)

#define ISSUE_X(cc) do {                                                    \
    _Pragma("unroll")                                                       \
    for (int q = 0; q < 2; ++q)                                             \
      _Pragma("unroll")                                                     \
      for (int b = 0; b < 4; ++b) {                                         \
        const float* _xp =                                                  \
            x + ((size_t)b * NV + (size_t)(cc) * JC + q * 256 + lane * 4) * 3; \
        xr[q][b][0] = *(const float4*)(_xp);                                \
        xr[q][b][1] = *(const float4*)(_xp + 4);                            \
        xr[q][b][2] = *(const float4*)(_xp + 8);                            \
      }                                                                     \
  } while (0)

#define COMPUTE_ROW(rr, slot) do {                                          \
    const float lf0[4] = {lr[slot][0].x, lr[slot][0].y,                     \
                          lr[slot][0].z, lr[slot][0].w};                    \
    const float lf1[4] = {lr[slot][1].x, lr[slot][1].y,                     \
                          lr[slot][1].z, lr[slot][1].w};                    \
    _Pragma("unroll")                                                       \
    for (int b = 0; b < 4; ++b) {                                           \
      const float x0[12] = {                                                \
          xr[0][b][0].x, xr[0][b][0].y, xr[0][b][0].z, xr[0][b][0].w,       \
          xr[0][b][1].x, xr[0][b][1].y, xr[0][b][1].z, xr[0][b][1].w,       \
          xr[0][b][2].x, xr[0][b][2].y, xr[0][b][2].z, xr[0][b][2].w};      \
      const float x1[12] = {                                                \
          xr[1][b][0].x, xr[1][b][0].y, xr[1][b][0].z, xr[1][b][0].w,       \
          xr[1][b][1].x, xr[1][b][1].y, xr[1][b][1].z, xr[1][b][1].w,       \
          xr[1][b][2].x, xr[1][b][2].y, xr[1][b][2].z, xr[1][b][2].w};      \
      _Pragma("unroll")                                                     \
      for (int j = 0; j < 4; ++j)                                           \
        _Pragma("unroll")                                                   \
        for (int d = 0; d < 3; ++d) {                                       \
          acc[rr][b * 3 + d] =                                              \
              fmaf(lf0[j], x0[j * 3 + d], acc[rr][b * 3 + d]);              \
          acc[rr][b * 3 + d] =                                              \
              fmaf(lf1[j], x1[j * 3 + d], acc[rr][b * 3 + d]);              \
        }                                                                   \
    }                                                                       \
  } while (0)

// One row-chunk step. Issue L three rows ahead; exact FIFO waits:
//   np==0: WAITV(2)  -> retires x(c) + older L rows (x needed now)
//   else : WAITV(4)  -> retires L(n+1), guarantees L(n) long done
// Last chunk: stop issuing at np>=5, drain 4->2->0 at the tail.
#define STEP(cc, np, LAST) do {                                             \
    if (!(LAST) || (np) < 5) {                                              \
      ISSUE_L((cc) * 8 + (np) + 3, ((np) + 3) & 3);                         \
      FENCE;                                                                \
    }                                                                       \
    if (LAST) {                                                             \
      if ((np) == 7)      WAITV(0);                                         \
      else if ((np) == 6) WAITV(2);                                         \
      else if ((np) == 0) WAITV(2);                                         \
      else                WAITV(4);                                         \
    } else {                                                                \
      if ((np) == 0)      WAITV(2);                                         \
      else                WAITV(4);                                         \
    }                                                                       \
    COMPUTE_ROW(np, (np) & 3);                                              \
    FENCE;                                                                  \
    if (!(LAST) && (np) == 7) { ISSUE_X((cc) + 1); FENCE; }                 \
  } while (0)

  // ---- prologue: x(0) first (oldest in FIFO), then L rows 0,1,2 ----
  ISSUE_X(0); FENCE;
  ISSUE_L(0, 0); ISSUE_L(1, 1); ISSUE_L(2, 2); FENCE;

#pragma unroll 1
  for (int c = 0; c < NCH - 1; ++c) {
    STEP(c, 0, false); STEP(c, 1, false); STEP(c, 2, false); STEP(c, 3, false);
    STEP(c, 4, false); STEP(c, 5, false); STEP(c, 6, false); STEP(c, 7, false);
  }
  STEP(NCH - 1, 0, true); STEP(NCH - 1, 1, true);
  STEP(NCH - 1, 2, true); STEP(NCH - 1, 3, true);
  STEP(NCH - 1, 4, true); STEP(NCH - 1, 5, true);
  STEP(NCH - 1, 6, true); STEP(NCH - 1, 7, true);

  // ---- butterfly-reduce each (row, b*3+d) over 64 lanes, square ----
  float s[4] = {0.f, 0.f, 0.f, 0.f};
#pragma unroll
  for (int r = 0; r < RPW; ++r)
#pragma unroll
    for (int k = 0; k < 12; ++k) {
      float v = acc[r][k];
#pragma unroll
      for (int off = 32; off > 0; off >>= 1)
        v += __shfl_xor(v, off, 64);
      s[k / 3] += v * v;
    }

  if (lane == 0) {
#pragma unroll
    for (int b = 0; b < 4; ++b) atomicAdd(&out[b], s[b]);
  }
}

extern "C" void kernel_launch(void* const* d_in, const int* in_sizes, int n_in,
                              void* d_out, int out_size, void* d_ws, size_t ws_size,
                              hipStream_t stream) {
  const float* x = (const float*)d_in[0];
  const float* L = (const float*)d_in[1];
  float* out = (float*)d_out;

  // Harness poisons d_out with 0xAA and never re-poisons between replays.
  hipMemsetAsync(out, 0, out_size * sizeof(float), stream);

  const int nblocks = NV / RPW;  // 2048 one-wave blocks, 8 waves/CU resident
  lap_loss_kernel<<<nblocks, 64, 0, stream>>>(x, L, out);
}

// Round 12
// 216.851 us; speedup vs baseline: 1.7208x; 1.7208x over previous
//
#include <hip/hip_runtime.h>

#define NV 16384
#define BROWS 32          // L rows per block
#define JT 256            // j-tile width (floats); tile = 32 KB
#define NT (NV / JT)      // 64 tiles
#define THREADS 256

typedef const __attribute__((address_space(1))) void* as1_ptr;
typedef __attribute__((address_space(3))) void* as3_ptr;

__device__ __forceinline__ void gload_lds16(const float* g, float* l) {
  __builtin_amdgcn_global_load_lds((as1_ptr)g, (as3_ptr)l, 16, 0, 0);
}

#define FENCE asm volatile("" ::: "memory")
#define WAITV(n) asm volatile("s_waitcnt vmcnt(" #n ")" ::: "memory")

__global__ __launch_bounds__(THREADS, 2) void lap_loss_kernel(
    const float* __restrict__ x, const float* __restrict__ L,
    float* __restrict__ out) {
  __shared__ float lbuf[2][BROWS][JT];  // 2 x 32 KB double buffer

  const int lane = threadIdx.x & 63;
  const int w    = threadIdx.x >> 6;     // wave id == batch index b
  const size_t i0 = (size_t)blockIdx.x * BROWS;

  // j-phase rotation: each block starts its column sweep at a different
  // tile and wraps. Decorrelates the j-window (-> HBM channel subset)
  // across blocks; without it the whole chip sweeps j in lockstep.
  const int phase = (int)(blockIdx.x & (NT - 1));

  // wave w stages rows i0+8w .. i0+8w+7; lane covers 16B of each row
  const float* gL[8];
#pragma unroll
  for (int r = 0; r < 8; ++r)
    gL[r] = L + (i0 + 8 * w + r) * NV + lane * 4;

  // wave w's x stream: x[w][j][d], lane owns j-quad 4*lane (48B)
  const float* gx = x + (size_t)w * NV * 3 + lane * 12;

  float acc[BROWS][3];
#pragma unroll
  for (int r = 0; r < BROWS; ++r)
#pragma unroll
    for (int d = 0; d < 3; ++d) acc[r][d] = 0.f;

  // ---- prologue: x(TI(0)) regs, then the 8 gl_lds for tile TI(0) ----
  const size_t j0 = (size_t)phase * JT;
  float4 xc0 = *(const float4*)(gx + j0 * 3 + 0);
  float4 xc1 = *(const float4*)(gx + j0 * 3 + 4);
  float4 xc2 = *(const float4*)(gx + j0 * 3 + 8);
  FENCE;
#pragma unroll
  for (int r = 0; r < 8; ++r)
    gload_lds16(gL[r] + j0, &lbuf[0][8 * w + r][0]);
  FENCE;

#pragma unroll 1
  for (int t = 0; t < NT; ++t) {
    const int cur = t & 1;

    float4 xn0, xn1, xn2;
    if (t + 1 < NT) {
      const size_t jn = (size_t)((t + 1 + phase) & (NT - 1)) * JT;
      // 1) gl_lds prefetch L(TI(t+1)) FIRST (older than the x prefetch)
#pragma unroll
      for (int r = 0; r < 8; ++r)
        gload_lds16(gL[r] + jn, &lbuf[cur ^ 1][8 * w + r][0]);
      FENCE;
      // 2) x(TI(t+1)) prefetch LAST -> youngest in the vmem queue
      const float* gxn = gx + jn * 3;
      xn0 = *(const float4*)(gxn + 0);
      xn1 = *(const float4*)(gxn + 4);
      xn2 = *(const float4*)(gxn + 8);
      FENCE;
      // 3) retire L(t)x8 + x(t)x3 (a full tile old -> no stall);
      //    keep L(t+1)x8 + x(t+1)x3 = 11 in flight across barrier+compute
      WAITV(11);
    } else {
      WAITV(0);
    }
    __builtin_amdgcn_s_barrier();
    FENCE;

    // 4) compute tile TI(t): 32 rows x 12 FMAs per lane-j-quad, batch w
    {
      const float xf[12] = {xc0.x, xc0.y, xc0.z, xc0.w,
                            xc1.x, xc1.y, xc1.z, xc1.w,
                            xc2.x, xc2.y, xc2.z, xc2.w};
#pragma unroll
      for (int r = 0; r < BROWS; ++r) {
        float4 lv = *(const float4*)&lbuf[cur][r][lane * 4];
        const float lf[4] = {lv.x, lv.y, lv.z, lv.w};
#pragma unroll
        for (int jj = 0; jj < 4; ++jj)
#pragma unroll
          for (int d = 0; d < 3; ++d)
            acc[r][d] = fmaf(lf[jj], xf[jj * 3 + d], acc[r][d]);
      }
    }

    FENCE;
    __builtin_amdgcn_s_barrier();  // all waves done reading lbuf[cur]
    FENCE;

    xc0 = xn0; xc1 = xn1; xc2 = xn2;
  }

  // ---- butterfly-reduce each (row,d) partial over 64 lanes, square ----
  float s = 0.f;
#pragma unroll
  for (int r = 0; r < BROWS; ++r)
#pragma unroll
    for (int d = 0; d < 3; ++d) {
      float v = acc[r][d];
#pragma unroll
      for (int off = 32; off > 0; off >>= 1)
        v += __shfl_xor(v, off, 64);
      s += v * v;
    }

  if (lane == 0) atomicAdd(&out[w], s);  // wave w owns batch w
}

extern "C" void kernel_launch(void* const* d_in, const int* in_sizes, int n_in,
                              void* d_out, int out_size, void* d_ws, size_t ws_size,
                              hipStream_t stream) {
  const float* x = (const float*)d_in[0];
  const float* L = (const float*)d_in[1];
  float* out = (float*)d_out;

  // Harness poisons d_out with 0xAA and never re-poisons between replays.
  hipMemsetAsync(out, 0, out_size * sizeof(float), stream);

  const int nblocks = NV / BROWS;  // 512 blocks = exactly 2 resident per CU
  lap_loss_kernel<<<nblocks, THREADS, 0, stream>>>(x, L, out);
}